// Round 1
// baseline (737.699 us; speedup 1.0000x reference)
//
#include <hip/hip_runtime.h>
#include <hip/hip_bf16.h>

#define N_SEGMENTS 50000
#define N_ROWS     1600000
#define N_FEAT     64

// One lane per (row, feature) element. A 64-lane wave covers exactly one
// 256-byte input row -> perfectly coalesced global_load_dword.
// idx[row] is wave-uniform (all 64 lanes read the same address -> broadcast).
__global__ void seg_sum_atomic(const float* __restrict__ in,
                               const int*   __restrict__ idx,
                               float*       __restrict__ out) {
    long long t   = (long long)blockIdx.x * blockDim.x + threadIdx.x;
    long long row = t >> 6;          // t / 64
    int       c   = (int)(t & 63);   // feature/column
    if (row < (long long)N_ROWS) {
        int s = idx[row];
        float v = in[row * N_FEAT + c];
        atomicAdd(out + (long long)s * N_FEAT + c, v);
    }
}

extern "C" void kernel_launch(void* const* d_in, const int* in_sizes, int n_in,
                              void* d_out, int out_size, void* d_ws, size_t ws_size,
                              hipStream_t stream) {
    const float* in  = (const float*)d_in[0];
    const int*   idx = (const int*)d_in[1];
    float*       out = (float*)d_out;

    // Output is poisoned (0xAA) before every timed call -> zero it ourselves.
    // hipMemsetAsync on the capture stream is graph-capture safe.
    hipMemsetAsync(d_out, 0, (size_t)out_size * sizeof(float), stream);

    const long long total = (long long)N_ROWS * N_FEAT;   // 102.4M lanes
    const int block = 256;
    const long long grid = (total + block - 1) / block;   // 400,000 blocks

    seg_sum_atomic<<<(unsigned)grid, block, 0, stream>>>(in, idx, out);
}